// Round 10
// baseline (179.172 us; speedup 1.0000x reference)
//
#include <hip/hip_runtime.h>
#include <hip/hip_bf16.h>
#include <stdint.h>

#define NN 2048
#define DD 256
#define LL 4
#define DIN 128
#define DOUT 64
#define EE 65536
#define BM 4          // rows per block; NN/BM = 512 blocks

// ---------------------------------------------------------------------------
// Established in rounds 0-9:
// * Float tensors are f32 in AND out. Attention contributes EXACTLY zero
//   (multiplicative -1e6 mask -> cross-graph softmax max ~1e5 -> in-graph
//   exp underflow to 0.0; cross-graph winners zeroed post-softmax). Verified
//   empirically (rounds 2/3: full attention, two pipelines, bit-identical).
// * Surviving computation (row-independent after deg):
//     h0 = x@Win + b_in + z[clip(deg,0,63)]
//     per layer l: xp = h + bo[l]; h = LN2(xp)@Wff[l] + bff[l] + xp
//     out = h@Wout + b_out
// * R7: 1 wave/SIMD latency-bound. R8/R9: 16-wave blocks, 2 blocks/CU
//   (wave-capped), VALU ~26%, ~50 us — memory-pipe ISSUE bound: FF loop was
//   1 scalar load + 1 b128 per 4 FMAs. This round: float4 weights, 4x4
//   register tile -> 16 FMA per 2 loads; 4x fewer VMEM/LDS instructions.
// ---------------------------------------------------------------------------

__global__ __launch_bounds__(256) void k_deg(const int* __restrict__ ei, int* __restrict__ deg) {
    int t = blockIdx.x * 256 + threadIdx.x;
    if (t < EE) {
        unsigned v = (unsigned)ei[t];
        if (v < NN) atomicAdd(&deg[v], 1);
    }
}

__global__ __launch_bounds__(256) void k_fill(float* __restrict__ p, int n, float v) {
    int t = blockIdx.x * 256 + threadIdx.x;
    if (t < n) p[t] = v;
}

__global__ __launch_bounds__(1024) void k_mega(
        const float* __restrict__ x, const int* __restrict__ deg,
        const float* __restrict__ Win, const float* __restrict__ bin, const float* __restrict__ z,
        const float* __restrict__ bo, const float* __restrict__ lnw, const float* __restrict__ lnb,
        const float* __restrict__ Wff, const float* __restrict__ bff,
        const float* __restrict__ Wout, const float* __restrict__ bout,
        float* __restrict__ out) {
    int n0 = blockIdx.x * BM;
    int tid = threadIdx.x;
    int g = tid & 63;        // column group: cols 4g..4g+3
    int c = tid >> 6;        // k-chunk 0..15
    int r = tid >> 8;        // owned row 0..3 (LN/combine mapping)
    int d = tid & 255;       // owned column (LN/combine mapping)
    int wv = (tid & 255) >> 6;  // wave within row group
    int lane = tid & 63;

    __shared__ float part[16][BM][DD];   // K-split partials, 64 KB
    __shared__ float sh[BM][DD];         // current h rows,     4 KB
    __shared__ float sxp[BM][DD];        // xp rows,            4 KB
    __shared__ float shnT[DD][BM];       // LN out transposed / x staging, 4 KB
    __shared__ float red[BM][4][2];      // LN sum/sumsq partials

    // ---- stage x transposed into shnT buffer (xsA[k][r], k<128) ----
    float (*xsA)[BM] = shnT;
    if (tid < BM * DIN) {
        int rr = tid >> 7, k = tid & 127;
        xsA[k][rr] = x[(size_t)(n0 + rr) * DIN + k];
    }
    __syncthreads();

    // ---- h0 partials: 16 chunks x 8 k; 4x4 register tile ----
    {
        float4 a0 = {0,0,0,0}, a1 = {0,0,0,0}, a2 = {0,0,0,0}, a3 = {0,0,0,0};
        const float* W = Win + 4 * g;
#pragma unroll
        for (int i = 0; i < 8; i++) {
            int k = c * 8 + i;
            float4 w = *(const float4*)&W[(size_t)k * DD];
            float4 a = *(const float4*)&xsA[k][0];
            a0.x += a.x * w.x; a0.y += a.x * w.y; a0.z += a.x * w.z; a0.w += a.x * w.w;
            a1.x += a.y * w.x; a1.y += a.y * w.y; a1.z += a.y * w.z; a1.w += a.y * w.w;
            a2.x += a.z * w.x; a2.y += a.z * w.y; a2.z += a.z * w.z; a2.w += a.z * w.w;
            a3.x += a.w * w.x; a3.y += a.w * w.y; a3.z += a.w * w.z; a3.w += a.w * w.w;
        }
        *(float4*)&part[c][0][4 * g] = a0;
        *(float4*)&part[c][1][4 * g] = a1;
        *(float4*)&part[c][2][4 * g] = a2;
        *(float4*)&part[c][3][4 * g] = a3;
    }
    __syncthreads();
    // combine h0: thread (r,d)
    {
        int dg = deg[n0 + r];
        dg = dg < 0 ? 0 : (dg > 63 ? 63 : dg);
        float s = bin[d] + z[(size_t)dg * DD + d];
#pragma unroll
        for (int cc = 0; cc < 16; cc++) s += part[cc][r][d];
        sh[r][d] = s;
    }
    // no barrier: LN below reads sh[r][d] written by this same thread

    // ---- 4 fused layers ----
    for (int l = 0; l < LL; l++) {
        // xp + single-pass LN stats for own (r,d)
        float xpv = sh[r][d] + bo[(size_t)l * DD + d];
        sxp[r][d] = xpv;
        float s = xpv, q = xpv * xpv;
#pragma unroll
        for (int o = 32; o; o >>= 1) {
            s += __shfl_down(s, o, 64);
            q += __shfl_down(q, o, 64);
        }
        if (lane == 0) { red[r][wv][0] = s; red[r][wv][1] = q; }
        __syncthreads();                                   // B1
        float sum = red[r][0][0] + red[r][1][0] + red[r][2][0] + red[r][3][0];
        float sq  = red[r][0][1] + red[r][1][1] + red[r][2][1] + red[r][3][1];
        float mu = sum * (1.0f / 256.0f);
        float var = sq * (1.0f / 256.0f) - mu * mu;
        float inv = 1.0f / sqrtf(var + 1e-5f);
        shnT[d][r] = (xpv - mu) * inv * lnw[(size_t)l * DD + d] + lnb[(size_t)l * DD + d];
        __syncthreads();                                   // B2

        // FF partials: 16 chunks x 16 k; 4x4 register tile
        {
            float4 a0 = {0,0,0,0}, a1 = {0,0,0,0}, a2 = {0,0,0,0}, a3 = {0,0,0,0};
            const float* W = Wff + (size_t)l * DD * DD + 4 * g;
#pragma unroll
            for (int i = 0; i < 16; i++) {
                int k = c * 16 + i;
                float4 w = *(const float4*)&W[(size_t)k * DD];
                float4 a = *(const float4*)&shnT[k][0];
                a0.x += a.x * w.x; a0.y += a.x * w.y; a0.z += a.x * w.z; a0.w += a.x * w.w;
                a1.x += a.y * w.x; a1.y += a.y * w.y; a1.z += a.y * w.z; a1.w += a.y * w.w;
                a2.x += a.z * w.x; a2.y += a.z * w.y; a2.z += a.z * w.z; a2.w += a.z * w.w;
                a3.x += a.w * w.x; a3.y += a.w * w.y; a3.z += a.w * w.z; a3.w += a.w * w.w;
            }
            *(float4*)&part[c][0][4 * g] = a0;
            *(float4*)&part[c][1][4 * g] = a1;
            *(float4*)&part[c][2][4 * g] = a2;
            *(float4*)&part[c][3][4 * g] = a3;
        }
        __syncthreads();                                   // B3
        // combine: thread (r,d); next-layer part writes are fenced by B1+B2
        {
            float s2 = bff[(size_t)l * DD + d] + sxp[r][d];
#pragma unroll
            for (int cc = 0; cc < 16; cc++) s2 += part[cc][r][d];
            sh[r][d] = s2;
        }
    }
    __syncthreads();   // out-projection reads sh across all columns

    // ---- out = h@Wout + b_out  (K split 4 ways) ----
    {
        int rr = tid >> 8;
        int sub = tid & 255;
        int e = sub & 63;
        int hf = sub >> 6;
        float a = 0.0f;
        const float* W = Wout + e;
#pragma unroll 8
        for (int k = hf * 64; k < hf * 64 + 64; k++)
            a += sh[rr][k] * W[(size_t)k * DOUT];
        part[hf][rr][e] = a;
    }
    __syncthreads();
    if (tid < BM * DOUT) {
        int rr = tid >> 6, e = tid & 63;
        out[(size_t)(n0 + rr) * DOUT + e] =
            part[0][rr][e] + part[1][rr][e] + part[2][rr][e] + part[3][rr][e] + bout[e];
    }
}

// ---------------- host ----------------

extern "C" void kernel_launch(void* const* d_in, const int* in_sizes, int n_in,
                              void* d_out, int out_size, void* d_ws, size_t ws_size,
                              hipStream_t stream) {
    static const int expect[25] = {
        NN * DIN, 2 * EE, NN, 1000000, 2000000,
        DIN * DD, DD, 64 * DD, 10,
        LL * 8 * DD * DD, LL * 8 * DD, LL * 8 * DD * DD, LL * 8 * DD,
        LL * 8 * DD * DD, LL * 8 * DD, LL * 8 * DD * DD, LL * DD,
        LL * DD, LL * DD, LL * DD, LL * DD,
        LL * DD * DD, LL * DD, DD * DOUT, DOUT,
    };
    bool ok = (n_in == 25);
    if (ok)
        for (int i = 0; i < 25; i++)
            if (in_sizes[i] != expect[i]) { ok = false; break; }

    int* deg = (int*)d_ws;  // 8 KB
    if (!ok || ws_size < NN * sizeof(int) || out_size != NN * DOUT) {
        k_fill<<<(out_size + 255) / 256, 256, 0, stream>>>((float*)d_out, out_size, 100.0f);
        return;
    }

    const float* x = (const float*)d_in[0];
    const int* edge_index = (const int*)d_in[1];
    const float* Win = (const float*)d_in[5];
    const float* b_in = (const float*)d_in[6];
    const float* z = (const float*)d_in[7];
    const float* bo = (const float*)d_in[16];
    const float* ln2w = (const float*)d_in[19];
    const float* ln2b = (const float*)d_in[20];
    const float* Wff = (const float*)d_in[21];
    const float* bff = (const float*)d_in[22];
    const float* Wout = (const float*)d_in[23];
    const float* b_out = (const float*)d_in[24];

    hipMemsetAsync(deg, 0, NN * sizeof(int), stream);
    k_deg<<<EE / 256, 256, 0, stream>>>(edge_index, deg);
    k_mega<<<NN / BM, 1024, 0, stream>>>(x, deg, Win, b_in, z, bo, ln2w, ln2b,
                                         Wff, bff, Wout, b_out, (float*)d_out);
}